// Round 5
// baseline (344.436 us; speedup 1.0000x reference)
//
#include <hip/hip_runtime.h>
#include <math.h>

// ---------------------------------------------------------------------------
// GCN: h1 = relu(norm_agg(x@W1)+b1); h2 = norm_agg(h1@W2)+b2;
//      g = mean_pool(h2, batch); out = relu(g@W3+b3)@W4 + b4
// R12 algebra: norm_agg(x@W) = norm_agg_raw(x)@W and pooling commutes with
// @W2+b2, so: P = aggR(x); h1 = relu(P@W1+b1); Q = aggR(h1) pooled; head
// applies W2,b2 then W3/W4. ONE GEMM total (W2 folded into 512-graph head).
// aggR scales by dinv[src] in-register per edge (src-sorted -> sequential
// dinv loads), self term (X[d]*dinv[d]+acc)*dinv[d].
// Build (block-granular only): LDS histogram over 3125 dst-blocks -> 1-block
// barrier-light scan -> two-level line-dense scatter -> per-block sort
// (key = dstLocal[4:3], src>>11) exactly partitioning each segment into
// FOUR 8-dst sub-segments (per-task [segLo,segHi)).
// Aggregation (R12): ONE wave per 8-dst task (12500 tasks, 2 KB acc, 8 KB
// LDS/block) -- front discipline kept (every wave starts at fraction 0 of
// its own src-sorted sub-segment; R8 showed mid-segment starts widen the L2
// band). Rounds of 32 clamped branch-free gathers; accumulates guarded by
// wave-uniform k<rem and 2-bit dst filter (= oversize-segment fallback).
// ---------------------------------------------------------------------------

#define NBLK 3125  // (100000+31)/32; guarded generically below

__global__ __launch_bounds__(256) void k_init(float* gsum, int* blockCnt,
                                              int gsz, int nblk) {
  int i = blockIdx.x * 256 + threadIdx.x;
  if (i < gsz) gsum[i] = 0.f;
  if (i < nblk + 64) blockCnt[i] = 0;
}

// Histogram of dst>>5 into nblk bins via LDS (12.8 KB), merged to global.
__global__ __launch_bounds__(256) void k_histB(const int* __restrict__ dst,
                                               int* __restrict__ blockCnt,
                                               int e, int nblk) {
  __shared__ int h[3200];
  int t = threadIdx.x;
  for (int i = t; i < 3200; i += 256) h[i] = 0;
  __syncthreads();
  int base = blockIdx.x * 8192;
#pragma unroll
  for (int k = 0; k < 32; ++k) {
    int i = base + k * 256 + t;
    if (i < e) atomicAdd(&h[dst[i] >> 5], 1);
  }
  __syncthreads();
  for (int i = t; i < nblk; i += 256) {
    int v = h[i];
    if (v) atomicAdd(&blockCnt[i], v);
  }
}

// Single-block exclusive scan of blockCnt[nblk]; writes blockBase (nblk+1,
// last = total), blockCursor (=base), bucketCursor (every 64th block).
// Barrier-light: per-thread chunk sum, shfl wave scan, one LDS exchange,
// sequential per-thread prefix writeback (~2 barriers).
__global__ __launch_bounds__(256) void k_scan(const int* __restrict__ blockCnt,
                                              int* __restrict__ blockBase,
                                              int* __restrict__ blockCursor,
                                              int* __restrict__ bucketCursor,
                                              int nblk, int nbuck) {
  __shared__ int wsum[4];
  int t = threadIdx.x;
  int w = t >> 6, lane = t & 63;
  int ch = (nblk + 255) >> 8;  // chunk per thread (13 for nblk=3125)
  int lo = t * ch;
  int hi = lo + ch;
  if (hi > nblk) hi = nblk;
  int s = 0;
  for (int i = lo; i < hi; ++i) s += blockCnt[i];
  // inclusive scan of per-thread sums within wave (no barriers)
  int inc = s;
  for (int off = 1; off < 64; off <<= 1) {
    int u = __shfl_up(inc, off);
    if (lane >= off) inc += u;
  }
  if (lane == 63) wsum[w] = inc;
  __syncthreads();
  int wpre = 0;
  for (int i = 0; i < w; ++i) wpre += wsum[i];
  int run = wpre + inc - s;  // exclusive prefix for this thread's chunk
  for (int i = lo; i < hi; ++i) {
    int v = blockCnt[i];
    blockBase[i] = run;
    blockCursor[i] = run;
    if ((i & 63) == 0 && (i >> 6) < nbuck) bucketCursor[i >> 6] = run;
    run += v;
  }
  if (t == 0) blockBase[nblk] = wsum[0] + wsum[1] + wsum[2] + wsum[3];
}

// Pass 1: bin edges into coarse buckets (2048 nodes each) with range-dense
// writes. Entry = (dstLow6<<22) | (src<<5) | dstLocal.
__global__ __launch_bounds__(256) void k_p1(const int* __restrict__ src,
                                            const int* __restrict__ dst,
                                            int* __restrict__ bucketCursor,
                                            int* __restrict__ tmp, int e) {
  __shared__ int hist[64];
  __shared__ int gbase[64];
  int t = threadIdx.x;
  int base = blockIdx.x * 2048;
  if (t < 64) hist[t] = 0;
  __syncthreads();
  int ent[8], rk[8], bk[8];
#pragma unroll
  for (int k = 0; k < 8; ++k) {
    int i = base + k * 256 + t;
    bool v = i < e;
    int s = v ? src[i] : 0;
    int d = v ? dst[i] : 0;
    bk[k] = d >> 11;
    ent[k] = (((d >> 5) & 63) << 22) | (s << 5) | (d & 31);
    rk[k] = v ? atomicAdd(&hist[bk[k]], 1) : -1;
  }
  __syncthreads();
  if (t < 64 && hist[t] > 0) gbase[t] = atomicAdd(&bucketCursor[t], hist[t]);
  __syncthreads();
#pragma unroll
  for (int k = 0; k < 8; ++k)
    if (rk[k] >= 0) tmp[gbase[bk[k]] + rk[k]] = ent[k];
}

// Pass 2: within each bucket (8 slices/bucket), bin entries to their dst-block
// segment (64 bins), range-dense writes; strip top 6 bits for final csr.
__global__ __launch_bounds__(256) void k_p2(const int* __restrict__ blockBase,
                                            const int* __restrict__ tmp,
                                            int* __restrict__ blockCursor,
                                            int* __restrict__ csr, int nblk) {
  __shared__ int hist[64];
  __shared__ int gbase[64];
  int b = blockIdx.x >> 3;
  int sl = blockIdx.x & 7;
  int hiIdx = (b + 1) << 6;
  if (hiIdx > nblk) hiIdx = nblk;
  int lo_b = blockBase[b << 6];
  int hi_b = blockBase[hiIdx];
  int len = hi_b - lo_b;
  int lo = lo_b + (int)(((long long)len * sl) >> 3);
  int hi = lo_b + (int)(((long long)len * (sl + 1)) >> 3);
  int t = threadIdx.x;
  for (int rbase = lo; rbase < hi; rbase += 2048) {
    if (t < 64) hist[t] = 0;
    __syncthreads();
    int ent[8], rk[8], bin[8];
#pragma unroll
    for (int k = 0; k < 8; ++k) {
      int i = rbase + k * 256 + t;
      bool v = i < hi;
      int en = v ? tmp[i] : 0;
      ent[k] = en;
      bin[k] = en >> 22;
      rk[k] = v ? atomicAdd(&hist[bin[k]], 1) : -1;
    }
    __syncthreads();
    if (t < 64 && hist[t] > 0)
      gbase[t] = atomicAdd(&blockCursor[(b << 6) + t], hist[t]);
    __syncthreads();
#pragma unroll
    for (int k = 0; k < 8; ++k)
      if (rk[k] >= 0) csr[gbase[bin[k]] + rk[k]] = ent[k] & 0x3FFFFF;
    __syncthreads();
  }
}

// Per-node-block (32 dsts): count degrees -> dinv, then counting-sort the
// packed segment by (dstLocal[4:3], src>>11) -- EXACT partition into four
// 8-dst quarters (+ src-locality within each). Emits per-8-task [segLo,segHi).
// Oversize segments (>1024, ~22-sigma) keep unsplit defaults: all four tasks
// sweep the full range; k_agg's 2-bit dst filter keeps it correct.
__global__ __launch_bounds__(256) void k_bsort(const int* __restrict__ blockBase,
                                               int* __restrict__ csr,
                                               float* __restrict__ dinv,
                                               int* __restrict__ segLo,
                                               int* __restrict__ segHi, int n) {
  __shared__ int in_sh[1024];
  __shared__ int out_sh[1024];
  __shared__ int hist[256];
  __shared__ int hscan[256];
  __shared__ int deg[32];
  int blk = blockIdx.x;
  int nodeBase = blk << 5;
  if (nodeBase >= n) return;
  int p0 = blockBase[blk];
  int p1 = blockBase[blk + 1];
  int seg = p1 - p0;
  int t = threadIdx.x;
  if (t < 32) deg[t] = 0;
  if (t < 4) {  // unsplit defaults (fallback; overwritten if sorted)
    segLo[4 * blk + t] = p0;
    segHi[4 * blk + t] = p1;
  }
  __syncthreads();
  for (int i = t; i < seg; i += 256) atomicAdd(&deg[csr[p0 + i] & 31], 1);
  __syncthreads();
  if (t < 32 && nodeBase + t < n)
    dinv[nodeBase + t] = 1.0f / sqrtf((float)(deg[t] + 1));
  if (seg <= 0 || seg > 1024) return;  // block-uniform
  hist[t] = 0;
  __syncthreads();
  for (int i = t; i < seg; i += 256) {
    int v = csr[p0 + i];
    in_sh[i] = v;
    // bin = dstLocal[4:3]*64 + src>>11
    atomicAdd(&hist[(((v >> 3) & 3) << 6) | ((v >> 16) & 63)], 1);
  }
  __syncthreads();
  if (t == 0) {
    int s = 0;
    for (int b = 0; b < 256; ++b) {
      hscan[b] = s;
      s += hist[b];
    }
  }
  __syncthreads();
  int q1 = hscan[64];   // count of quarter 0
  int q2 = hscan[128];  // quarters 0+1
  int q3 = hscan[192];  // quarters 0+1+2
  __syncthreads();      // all reads before scatter mutates hscan
  for (int i = t; i < seg; i += 256) {
    int v = in_sh[i];
    int pos = atomicAdd(&hscan[(((v >> 3) & 3) << 6) | ((v >> 16) & 63)], 1);
    out_sh[pos] = v;
  }
  __syncthreads();
  for (int i = t; i < seg; i += 256) csr[p0 + i] = out_sh[i];
  if (t == 0) {  // split boundaries (partition is exact)
    segHi[4 * blk + 0] = p0 + q1;
    segLo[4 * blk + 1] = p0 + q1;
    segHi[4 * blk + 1] = p0 + q2;
    segLo[4 * blk + 2] = p0 + q2;
    segHi[4 * blk + 2] = p0 + q3;
    segLo[4 * blk + 3] = p0 + q3;
  }
}

// Y[N,64] = relu(X[N,64] @ W[64,64] + bias)  (fused bias+relu epilogue).
__global__ __launch_bounds__(256) void k_gemm64br(const float* __restrict__ X,
                                                  const float* __restrict__ W,
                                                  const float* __restrict__ bias,
                                                  float* __restrict__ Y, int n) {
  __shared__ float Xs[64 * 65];
  __shared__ float Ws[64 * 64];
  int t = threadIdx.x;
  int r0 = blockIdx.x << 6;
  for (int i = t * 4; i < 4096; i += 1024)
    *(float4*)&Ws[i] = *(const float4*)&W[i];
  for (int s = t; s < 1024; s += 256) {
    int r = s >> 4, c4 = (s & 15) << 2;
    float4 v = make_float4(0.f, 0.f, 0.f, 0.f);
    if (r0 + r < n) v = *(const float4*)&X[(size_t)(r0 + r) * 64 + c4];
    Xs[r * 65 + c4 + 0] = v.x;
    Xs[r * 65 + c4 + 1] = v.y;
    Xs[r * 65 + c4 + 2] = v.z;
    Xs[r * 65 + c4 + 3] = v.w;
  }
  __syncthreads();
  int c4 = (t & 15) << 2;
  int rb = (t >> 4) << 2;
  float4 a0 = {0, 0, 0, 0}, a1 = {0, 0, 0, 0}, a2 = {0, 0, 0, 0}, a3 = {0, 0, 0, 0};
  for (int k = 0; k < 64; ++k) {
    float4 w = *(const float4*)&Ws[k * 64 + c4];
    float x0 = Xs[(rb + 0) * 65 + k];
    float x1 = Xs[(rb + 1) * 65 + k];
    float x2 = Xs[(rb + 2) * 65 + k];
    float x3 = Xs[(rb + 3) * 65 + k];
    a0.x += x0 * w.x; a0.y += x0 * w.y; a0.z += x0 * w.z; a0.w += x0 * w.w;
    a1.x += x1 * w.x; a1.y += x1 * w.y; a1.z += x1 * w.z; a1.w += x1 * w.w;
    a2.x += x2 * w.x; a2.y += x2 * w.y; a2.z += x2 * w.z; a2.w += x2 * w.w;
    a3.x += x3 * w.x; a3.y += x3 * w.y; a3.z += x3 * w.z; a3.w += x3 * w.w;
  }
  float4 bb = *(const float4*)&bias[c4];
  int r = r0 + rb;
  if (r + 0 < n) {
    a0.x = fmaxf(a0.x + bb.x, 0.f); a0.y = fmaxf(a0.y + bb.y, 0.f);
    a0.z = fmaxf(a0.z + bb.z, 0.f); a0.w = fmaxf(a0.w + bb.w, 0.f);
    *(float4*)&Y[(size_t)(r + 0) * 64 + c4] = a0;
  }
  if (r + 1 < n) {
    a1.x = fmaxf(a1.x + bb.x, 0.f); a1.y = fmaxf(a1.y + bb.y, 0.f);
    a1.z = fmaxf(a1.z + bb.z, 0.f); a1.w = fmaxf(a1.w + bb.w, 0.f);
    *(float4*)&Y[(size_t)(r + 1) * 64 + c4] = a1;
  }
  if (r + 2 < n) {
    a2.x = fmaxf(a2.x + bb.x, 0.f); a2.y = fmaxf(a2.y + bb.y, 0.f);
    a2.z = fmaxf(a2.z + bb.z, 0.f); a2.w = fmaxf(a2.w + bb.w, 0.f);
    *(float4*)&Y[(size_t)(r + 2) * 64 + c4] = a2;
  }
  if (r + 3 < n) {
    a3.x = fmaxf(a3.x + bb.x, 0.f); a3.y = fmaxf(a3.y + bb.y, 0.f);
    a3.z = fmaxf(a3.z + bb.z, 0.f); a3.w = fmaxf(a3.w + bb.w, 0.f);
    *(float4*)&Y[(size_t)(r + 3) * 64 + c4] = a3;
  }
}

// Aggregation (R12): one wave per 8-dst task, exclusive 2 KB acc, rounds of
// 32 with index prefetch. Gathers RAW rows + dinv[src] (scaled in-register).
// All 32 gathers issued unconditionally (clamped indices -> branch-free
// batch); accumulates guarded by wave-uniform k<rem AND dstLocal[4:3]==par
// (always true for split blocks; the filter is the oversize fallback).
// out[d] = (acc + X[d]*dinv[d]) * dinv[d]. POOL=0: store; POOL=1: gsum add.
template <int POOL>
__global__ __launch_bounds__(256) void k_agg(
    const float* __restrict__ X, const int* __restrict__ csr,
    const int* __restrict__ segLo, const int* __restrict__ segHi,
    const float* __restrict__ dinv, const int* __restrict__ batch,
    float* __restrict__ outv, float* __restrict__ gsum, int n, int ntask) {
  __shared__ float accs[4][8 * 64];  // 8 KB / block
  int t = threadIdx.x;
  int w = t >> 6, lane = t & 63;
  int task = blockIdx.x * 4 + w;
  if (task >= ntask) return;  // wave-uniform; no block syncs below
  int nodeBase = task << 3;
  int par = task & 3;  // dstLocal bits [4:3] owned by this task
  float* a = accs[w];
#pragma unroll
  for (int d = 0; d < 8; ++d) a[d * 64 + lane] = 0.f;
  int p0 = segLo[task];
  int p1 = segHi[task];
  int c = p1 - p0;
  if (c > 0) {
    int sub = lane & 31;
    int qlast = p1 - 1;
    int qq = p0 + sub;
    int pk = csr[qq < qlast ? qq : qlast];  // round-0 indices (32 in lanes)
    for (int rb = 0; rb < c; rb += 32) {
      int pk_next = 0;
      bool more = (rb + 32) < c;  // wave-uniform
      if (more) {
        int qn = p0 + rb + 32 + sub;
        pk_next = csr[qn < qlast ? qn : qlast];  // prefetch next round
      }
      int rem = c - rb;  // wave-uniform
      int ee[32];
#pragma unroll
      for (int k = 0; k < 32; ++k) ee[k] = __builtin_amdgcn_readlane(pk, k);
      // branch-free batch of 32 independent gathers (clamped dups at tail)
      float tv[32], dv[32];
#pragma unroll
      for (int k = 0; k < 32; ++k) {
        int sr = ee[k] >> 5;
        tv[k] = X[(size_t)sr * 64 + lane];
        dv[k] = dinv[sr];
      }
      // guarded accumulates (wave-uniform predicates)
#pragma unroll
      for (int k = 0; k < 32; ++k)
        if (k < rem && (((ee[k] >> 3) & 3) == par))
          a[(ee[k] & 7) * 64 + lane] += tv[k] * dv[k];
      pk = pk_next;
    }
  }
  for (int d = 0; d < 8; ++d) {
    int node = nodeBase + d;
    if (node >= n) break;
    float dn = dinv[node];
    float v = (a[d * 64 + lane] + X[(size_t)node * 64 + lane] * dn) * dn;
    if (POOL) {
      int g = batch[node];
      atomicAdd(&gsum[(size_t)g * 64 + lane], v);
    } else {
      outv[(size_t)node * 64 + lane] = v;
    }
  }
}

// Head: per-graph wave. m = gsum/cnt; g2 = m@W2+b2; g3 = relu(g2@W3+b3);
// out = g3@W4 + b4. Node count via binary search on sorted batch.
__global__ __launch_bounds__(256) void k_head(
    const float* __restrict__ gsum, const int* __restrict__ batch,
    const float* __restrict__ W2, const float* __restrict__ b2,
    const float* __restrict__ W3, const float* __restrict__ b3,
    const float* __restrict__ W4, const float* __restrict__ b4,
    float* __restrict__ out, int ng, int n) {
  int wid = (blockIdx.x * 256 + threadIdx.x) >> 6;
  int lane = threadIdx.x & 63;
  if (wid >= ng) return;
  int lo = 0, hi = n;
  while (lo < hi) {
    int mid = (lo + hi) >> 1;
    if (batch[mid] < wid) lo = mid + 1; else hi = mid;
  }
  int lb = lo;
  hi = n;
  while (lo < hi) {
    int mid = (lo + hi) >> 1;
    if (batch[mid] <= wid) lo = mid + 1; else hi = mid;
  }
  float cden = fmaxf((float)(lo - lb), 1.0f);
  float m = gsum[(size_t)wid * 64 + lane] / cden;
  float g2 = b2[lane];
  for (int k = 0; k < 64; ++k) {
    float mk = __shfl(m, k);
    g2 += mk * W2[k * 64 + lane];
  }
  float g3 = b3[lane];
  for (int k = 0; k < 64; ++k) {
    float gk = __shfl(g2, k);
    g3 += gk * W3[k * 64 + lane];
  }
  g3 = fmaxf(g3, 0.f);
  float r = g3 * W4[lane];
  for (int off = 32; off; off >>= 1) r += __shfl_down(r, off);
  if (lane == 0) out[wid] = r + b4[0];
}

extern "C" void kernel_launch(void* const* d_in, const int* in_sizes, int n_in,
                              void* d_out, int out_size, void* d_ws, size_t ws_size,
                              hipStream_t stream) {
  const float* x = (const float*)d_in[0];
  const int* edge = (const int*)d_in[1];   // [2, E] int32
  const int* batch = (const int*)d_in[2];  // [N] int32, sorted
  const float* W1 = (const float*)d_in[3];
  const float* b1 = (const float*)d_in[4];
  const float* W2 = (const float*)d_in[5];
  const float* b2 = (const float*)d_in[6];
  const float* W3 = (const float*)d_in[7];
  const float* b3 = (const float*)d_in[8];
  const float* W4 = (const float*)d_in[9];
  const float* b4 = (const float*)d_in[10];
  float* out = (float*)d_out;

  const int n = in_sizes[0] / 64;   // 100000
  const int e = in_sizes[1] / 2;    // 1600000
  const int ng = out_size;          // 512
  const int* src = edge;
  const int* dst = edge + e;

  // Workspace layout.
  char* ws = (char*)d_ws;
  size_t off = 0;
  auto alloc = [&](size_t bytes) -> void* {
    void* p = ws + off;
    off = (off + bytes + 255) & ~(size_t)255;
    return p;
  };
  float* A = (float*)alloc((size_t)n * 64 * 4);   // h1 (gemm output)
  float* B = (float*)alloc((size_t)n * 64 * 4);   // P (agg1 out); tmp in build
  float* dinv = (float*)alloc((size_t)n * 4);
  int* blockCnt = (int*)alloc(3264 * 4);
  int* blockBase = (int*)alloc(3264 * 4);
  int* blockCursor = (int*)alloc(3264 * 4);
  int* bucketCursor = (int*)alloc(64 * 4);
  int* segLo = (int*)alloc(12544 * 4);
  int* segHi = (int*)alloc(12544 * 4);
  int* csr = (int*)alloc((size_t)e * 4);
  float* gsum = (float*)alloc((size_t)ng * 64 * 4);
  int* tmp = (int*)B;  // build-time only; B not live yet

  const int nblk = (n + 31) / 32;        // 3125 dst-blocks
  const int nbuck = (nblk + 63) / 64;    // 49 coarse buckets
  const int ntask = 4 * nblk;            // 12500 8-dst agg tasks
  const int nagg = (ntask + 3) / 4;      // agg workgroups (3125): 4 tasks/blk
  const int gsz = ng * 64;

  int zmax = gsz > nblk + 64 ? gsz : nblk + 64;
  k_init<<<(zmax + 255) / 256, 256, 0, stream>>>(gsum, blockCnt, gsz, nblk);
  k_histB<<<(e + 8191) / 8192, 256, 0, stream>>>(dst, blockCnt, e, nblk);
  k_scan<<<1, 256, 0, stream>>>(blockCnt, blockBase, blockCursor, bucketCursor,
                                nblk, nbuck);
  k_p1<<<(e + 2047) / 2048, 256, 0, stream>>>(src, dst, bucketCursor, tmp, e);
  k_p2<<<nbuck * 8, 256, 0, stream>>>(blockBase, tmp, blockCursor, csr, nblk);
  k_bsort<<<nblk, 256, 0, stream>>>(blockBase, csr, dinv, segLo, segHi, n);

  // Layer 1: B = aggR(x) ; A = relu(B@W1 + b1)
  k_agg<0><<<nagg, 256, 0, stream>>>(x, csr, segLo, segHi, dinv, batch, B,
                                     gsum, n, ntask);
  k_gemm64br<<<(n + 63) / 64, 256, 0, stream>>>(B, W1, b1, A, n);
  // Layer 2: gsum += pooled aggR(A)
  k_agg<1><<<nagg, 256, 0, stream>>>(A, csr, segLo, segHi, dinv, batch, B,
                                     gsum, n, ntask);
  // Head: mean, @W2+b2, relu(@W3+b3), @W4+b4
  k_head<<<((size_t)ng * 64 + 255) / 256, 256, 0, stream>>>(
      gsum, batch, W2, b2, W3, b3, W4, b4, out, ng, n);
}

// Round 6
// 319.803 us; speedup vs baseline: 1.0770x; 1.0770x over previous
//
#include <hip/hip_runtime.h>
#include <math.h>

// ---------------------------------------------------------------------------
// GCN: h1 = relu(norm_agg(x@W1)+b1); h2 = norm_agg(h1@W2)+b2;
//      g = mean_pool(h2, batch); out = relu(g@W3+b3)@W4 + b4
// R13 algebra (one GEMM): norm_agg(x@W) = norm_agg_raw(x)@W; pooling commutes
// with @W2+b2; relu commutes with positive row scale.
//   P = x*dinv[row] (prescale, aliased on A)
//   B = aggS(P): B[d] = (sum_{src->d} P[src] + P[d]) * dinv[d]
//   A = relu(B@W1+b1)*dinv[row]  (fused GEMM epilogue)
//   gsum += pool( (sum A[src] + A[d]) * dinv[d] )
//   head: m@W2+b2 -> relu(@W3+b3) -> @W4+b4
// Agg = R11 config (proven best): ONE wave per 16-dst task, 6250 fronts --
// L2-miss traffic scales with front count (103/129/180 MB @ 3125/6250/12500
// fronts, R10/R11/R12); 6250 is the measured locality/occupancy sweet spot.
// No in-loop dinv (R12's second gather stream). 128-thr blocks (2 tasks) for
// finer retirement granularity. Rounds of 32 clamped branch-free gathers;
// accumulates guarded by wave-uniform k<rem + dst-bit4 filter (oversize
// fallback). Build: block-granular two-level scatter + per-block sort
// (key = dst-bit4, src>>11) emitting per-16-task [segLo,segHi).
// ---------------------------------------------------------------------------

#define NBLK 3125  // (100000+31)/32; guarded generically below

__global__ __launch_bounds__(256) void k_init(float* gsum, int* blockCnt,
                                              int gsz, int nblk) {
  int i = blockIdx.x * 256 + threadIdx.x;
  if (i < gsz) gsum[i] = 0.f;
  if (i < nblk + 64) blockCnt[i] = 0;
}

// Histogram of dst>>5 into nblk bins via LDS (12.8 KB), merged to global.
__global__ __launch_bounds__(256) void k_histB(const int* __restrict__ dst,
                                               int* __restrict__ blockCnt,
                                               int e, int nblk) {
  __shared__ int h[3200];
  int t = threadIdx.x;
  for (int i = t; i < 3200; i += 256) h[i] = 0;
  __syncthreads();
  int base = blockIdx.x * 8192;
#pragma unroll
  for (int k = 0; k < 32; ++k) {
    int i = base + k * 256 + t;
    if (i < e) atomicAdd(&h[dst[i] >> 5], 1);
  }
  __syncthreads();
  for (int i = t; i < nblk; i += 256) {
    int v = h[i];
    if (v) atomicAdd(&blockCnt[i], v);
  }
}

// Single-block exclusive scan of blockCnt[nblk]; barrier-light (~2 barriers).
__global__ __launch_bounds__(256) void k_scan(const int* __restrict__ blockCnt,
                                              int* __restrict__ blockBase,
                                              int* __restrict__ blockCursor,
                                              int* __restrict__ bucketCursor,
                                              int nblk, int nbuck) {
  __shared__ int wsum[4];
  int t = threadIdx.x;
  int w = t >> 6, lane = t & 63;
  int ch = (nblk + 255) >> 8;  // chunk per thread (13 for nblk=3125)
  int lo = t * ch;
  int hi = lo + ch;
  if (hi > nblk) hi = nblk;
  int s = 0;
  for (int i = lo; i < hi; ++i) s += blockCnt[i];
  int inc = s;
  for (int off = 1; off < 64; off <<= 1) {
    int u = __shfl_up(inc, off);
    if (lane >= off) inc += u;
  }
  if (lane == 63) wsum[w] = inc;
  __syncthreads();
  int wpre = 0;
  for (int i = 0; i < w; ++i) wpre += wsum[i];
  int run = wpre + inc - s;  // exclusive prefix for this thread's chunk
  for (int i = lo; i < hi; ++i) {
    int v = blockCnt[i];
    blockBase[i] = run;
    blockCursor[i] = run;
    if ((i & 63) == 0 && (i >> 6) < nbuck) bucketCursor[i >> 6] = run;
    run += v;
  }
  if (t == 0) blockBase[nblk] = wsum[0] + wsum[1] + wsum[2] + wsum[3];
}

// Pass 1: bin edges into coarse buckets (2048 nodes each) with range-dense
// writes. Entry = (dstLow6<<22) | (src<<5) | dstLocal.
__global__ __launch_bounds__(256) void k_p1(const int* __restrict__ src,
                                            const int* __restrict__ dst,
                                            int* __restrict__ bucketCursor,
                                            int* __restrict__ tmp, int e) {
  __shared__ int hist[64];
  __shared__ int gbase[64];
  int t = threadIdx.x;
  int base = blockIdx.x * 2048;
  if (t < 64) hist[t] = 0;
  __syncthreads();
  int ent[8], rk[8], bk[8];
#pragma unroll
  for (int k = 0; k < 8; ++k) {
    int i = base + k * 256 + t;
    bool v = i < e;
    int s = v ? src[i] : 0;
    int d = v ? dst[i] : 0;
    bk[k] = d >> 11;
    ent[k] = (((d >> 5) & 63) << 22) | (s << 5) | (d & 31);
    rk[k] = v ? atomicAdd(&hist[bk[k]], 1) : -1;
  }
  __syncthreads();
  if (t < 64 && hist[t] > 0) gbase[t] = atomicAdd(&bucketCursor[t], hist[t]);
  __syncthreads();
#pragma unroll
  for (int k = 0; k < 8; ++k)
    if (rk[k] >= 0) tmp[gbase[bk[k]] + rk[k]] = ent[k];
}

// Pass 2: within each bucket (8 slices/bucket), bin entries to their dst-block
// segment (64 bins), range-dense writes; strip top 6 bits for final csr.
__global__ __launch_bounds__(256) void k_p2(const int* __restrict__ blockBase,
                                            const int* __restrict__ tmp,
                                            int* __restrict__ blockCursor,
                                            int* __restrict__ csr, int nblk) {
  __shared__ int hist[64];
  __shared__ int gbase[64];
  int b = blockIdx.x >> 3;
  int sl = blockIdx.x & 7;
  int hiIdx = (b + 1) << 6;
  if (hiIdx > nblk) hiIdx = nblk;
  int lo_b = blockBase[b << 6];
  int hi_b = blockBase[hiIdx];
  int len = hi_b - lo_b;
  int lo = lo_b + (int)(((long long)len * sl) >> 3);
  int hi = lo_b + (int)(((long long)len * (sl + 1)) >> 3);
  int t = threadIdx.x;
  for (int rbase = lo; rbase < hi; rbase += 2048) {
    if (t < 64) hist[t] = 0;
    __syncthreads();
    int ent[8], rk[8], bin[8];
#pragma unroll
    for (int k = 0; k < 8; ++k) {
      int i = rbase + k * 256 + t;
      bool v = i < hi;
      int en = v ? tmp[i] : 0;
      ent[k] = en;
      bin[k] = en >> 22;
      rk[k] = v ? atomicAdd(&hist[bin[k]], 1) : -1;
    }
    __syncthreads();
    if (t < 64 && hist[t] > 0)
      gbase[t] = atomicAdd(&blockCursor[(b << 6) + t], hist[t]);
    __syncthreads();
#pragma unroll
    for (int k = 0; k < 8; ++k)
      if (rk[k] >= 0) csr[gbase[bin[k]] + rk[k]] = ent[k] & 0x3FFFFF;
    __syncthreads();
  }
}

// Per-node-block (32 dsts): count degrees -> dinv, then counting-sort the
// packed segment by (dst-bit4, src>>11) -- EXACT partition into two 16-dst
// halves (+ src-locality within each). Emits per-16-task [segLo,segHi).
// Oversize segments (>1024) keep unsplit defaults; k_agg's dst-bit4 filter
// keeps it correct.
__global__ __launch_bounds__(256) void k_bsort(const int* __restrict__ blockBase,
                                               int* __restrict__ csr,
                                               float* __restrict__ dinv,
                                               int* __restrict__ segLo,
                                               int* __restrict__ segHi, int n) {
  __shared__ int in_sh[1024];
  __shared__ int out_sh[1024];
  __shared__ int hist[128];
  __shared__ int hscan[129];
  __shared__ int deg[32];
  int blk = blockIdx.x;
  int nodeBase = blk << 5;
  if (nodeBase >= n) return;
  int p0 = blockBase[blk];
  int p1 = blockBase[blk + 1];
  int seg = p1 - p0;
  int t = threadIdx.x;
  if (t < 32) deg[t] = 0;
  if (t == 0) {  // unsplit defaults (fallback; overwritten if sorted)
    segLo[2 * blk] = p0;
    segHi[2 * blk] = p1;
    segLo[2 * blk + 1] = p0;
    segHi[2 * blk + 1] = p1;
  }
  __syncthreads();
  for (int i = t; i < seg; i += 256) atomicAdd(&deg[csr[p0 + i] & 31], 1);
  __syncthreads();
  if (t < 32 && nodeBase + t < n)
    dinv[nodeBase + t] = 1.0f / sqrtf((float)(deg[t] + 1));
  if (seg <= 0 || seg > 1024) return;  // block-uniform
  if (t < 128) hist[t] = 0;
  __syncthreads();
  for (int i = t; i < seg; i += 256) {
    int v = csr[p0 + i];
    in_sh[i] = v;
    // bin = dstBit4*64 + src>>11
    atomicAdd(&hist[((v & 16) << 2) | ((v >> 16) & 63)], 1);
  }
  __syncthreads();
  if (t == 0) {
    int s = 0;
    for (int b = 0; b < 128; ++b) {
      hscan[b] = s;
      s += hist[b];
    }
    hscan[128] = s;
  }
  __syncthreads();
  int cntLow = hscan[64];  // exact count of dst-bit4==0 entries
  __syncthreads();         // all reads of hscan[64] before scatter mutates it
  for (int i = t; i < seg; i += 256) {
    int v = in_sh[i];
    int pos = atomicAdd(&hscan[((v & 16) << 2) | ((v >> 16) & 63)], 1);
    out_sh[pos] = v;
  }
  __syncthreads();
  for (int i = t; i < seg; i += 256) csr[p0 + i] = out_sh[i];
  if (t == 0) {  // split boundaries (partition is exact)
    segHi[2 * blk] = p0 + cntLow;
    segLo[2 * blk + 1] = p0 + cntLow;
  }
}

// P[i] = x[i] * dinv[row]  (row scale; one float4 per thread).
__global__ __launch_bounds__(256) void k_prescale(const float* __restrict__ x,
                                                  const float* __restrict__ dinv,
                                                  float* __restrict__ P, int n) {
  int i = blockIdx.x * 256 + threadIdx.x;  // float4 index
  int total = n * 16;
  if (i >= total) return;
  float4 v = *(const float4*)&x[(size_t)i * 4];
  float s = dinv[i >> 4];
  v.x *= s; v.y *= s; v.z *= s; v.w *= s;
  *(float4*)&P[(size_t)i * 4] = v;
}

// Y[N,64] = relu(X[N,64] @ W[64,64] + bias) * dinv[row]
// (fused bias+relu+scale epilogue; output pre-scaled for layer-2 agg).
__global__ __launch_bounds__(256) void k_gemm64brs(const float* __restrict__ X,
                                                   const float* __restrict__ W,
                                                   const float* __restrict__ bias,
                                                   const float* __restrict__ dinv,
                                                   float* __restrict__ Y, int n) {
  __shared__ float Xs[64 * 65];
  __shared__ float Ws[64 * 64];
  int t = threadIdx.x;
  int r0 = blockIdx.x << 6;
  for (int i = t * 4; i < 4096; i += 1024)
    *(float4*)&Ws[i] = *(const float4*)&W[i];
  for (int s = t; s < 1024; s += 256) {
    int r = s >> 4, c4 = (s & 15) << 2;
    float4 v = make_float4(0.f, 0.f, 0.f, 0.f);
    if (r0 + r < n) v = *(const float4*)&X[(size_t)(r0 + r) * 64 + c4];
    Xs[r * 65 + c4 + 0] = v.x;
    Xs[r * 65 + c4 + 1] = v.y;
    Xs[r * 65 + c4 + 2] = v.z;
    Xs[r * 65 + c4 + 3] = v.w;
  }
  __syncthreads();
  int c4 = (t & 15) << 2;
  int rb = (t >> 4) << 2;
  float4 a0 = {0, 0, 0, 0}, a1 = {0, 0, 0, 0}, a2 = {0, 0, 0, 0}, a3 = {0, 0, 0, 0};
  for (int k = 0; k < 64; ++k) {
    float4 w = *(const float4*)&Ws[k * 64 + c4];
    float x0 = Xs[(rb + 0) * 65 + k];
    float x1 = Xs[(rb + 1) * 65 + k];
    float x2 = Xs[(rb + 2) * 65 + k];
    float x3 = Xs[(rb + 3) * 65 + k];
    a0.x += x0 * w.x; a0.y += x0 * w.y; a0.z += x0 * w.z; a0.w += x0 * w.w;
    a1.x += x1 * w.x; a1.y += x1 * w.y; a1.z += x1 * w.z; a1.w += x1 * w.w;
    a2.x += x2 * w.x; a2.y += x2 * w.y; a2.z += x2 * w.z; a2.w += x2 * w.w;
    a3.x += x3 * w.x; a3.y += x3 * w.y; a3.z += x3 * w.z; a3.w += x3 * w.w;
  }
  float4 bb = *(const float4*)&bias[c4];
  int r = r0 + rb;
  if (r + 0 < n) {
    float s0 = dinv[r + 0];
    a0.x = fmaxf(a0.x + bb.x, 0.f) * s0; a0.y = fmaxf(a0.y + bb.y, 0.f) * s0;
    a0.z = fmaxf(a0.z + bb.z, 0.f) * s0; a0.w = fmaxf(a0.w + bb.w, 0.f) * s0;
    *(float4*)&Y[(size_t)(r + 0) * 64 + c4] = a0;
  }
  if (r + 1 < n) {
    float s1 = dinv[r + 1];
    a1.x = fmaxf(a1.x + bb.x, 0.f) * s1; a1.y = fmaxf(a1.y + bb.y, 0.f) * s1;
    a1.z = fmaxf(a1.z + bb.z, 0.f) * s1; a1.w = fmaxf(a1.w + bb.w, 0.f) * s1;
    *(float4*)&Y[(size_t)(r + 1) * 64 + c4] = a1;
  }
  if (r + 2 < n) {
    float s2 = dinv[r + 2];
    a2.x = fmaxf(a2.x + bb.x, 0.f) * s2; a2.y = fmaxf(a2.y + bb.y, 0.f) * s2;
    a2.z = fmaxf(a2.z + bb.z, 0.f) * s2; a2.w = fmaxf(a2.w + bb.w, 0.f) * s2;
    *(float4*)&Y[(size_t)(r + 2) * 64 + c4] = a2;
  }
  if (r + 3 < n) {
    float s3 = dinv[r + 3];
    a3.x = fmaxf(a3.x + bb.x, 0.f) * s3; a3.y = fmaxf(a3.y + bb.y, 0.f) * s3;
    a3.z = fmaxf(a3.z + bb.z, 0.f) * s3; a3.w = fmaxf(a3.w + bb.w, 0.f) * s3;
    *(float4*)&Y[(size_t)(r + 3) * 64 + c4] = a3;
  }
}

// Aggregation (R13 = R11 hot loop): one wave per 16-dst task, exclusive 4 KB
// acc, rounds of 32 with index prefetch; operand rows are PRE-SCALED by
// dinv[src]. out[d] = (acc + X[d]) * dinv[d]. 128-thr blocks (2 tasks) for
// finer retirement. POOL=0: plain store; POOL=1: atomicAdd into gsum.
template <int POOL>
__global__ __launch_bounds__(128) void k_agg(
    const float* __restrict__ X, const int* __restrict__ csr,
    const int* __restrict__ segLo, const int* __restrict__ segHi,
    const float* __restrict__ dinv, const int* __restrict__ batch,
    float* __restrict__ outv, float* __restrict__ gsum, int n, int ntask) {
  __shared__ float accs[2][16 * 64];  // 8 KB / block
  int t = threadIdx.x;
  int w = t >> 6, lane = t & 63;
  int task = blockIdx.x * 2 + w;
  if (task >= ntask) return;  // wave-uniform; no block syncs below
  int nodeBase = task << 4;
  int par = task & 1;  // dst bit4 owned by this task
  float* a = accs[w];
#pragma unroll 4
  for (int d = 0; d < 16; ++d) a[d * 64 + lane] = 0.f;
  int p0 = segLo[task];
  int p1 = segHi[task];
  int c = p1 - p0;
  if (c > 0) {
    int sub = lane & 31;
    int qlast = p1 - 1;
    int qq = p0 + sub;
    int pk = csr[qq < qlast ? qq : qlast];  // round-0 indices (32 in lanes)
    for (int rb = 0; rb < c; rb += 32) {
      int pk_next = 0;
      bool more = (rb + 32) < c;  // wave-uniform
      if (more) {
        int qn = p0 + rb + 32 + sub;
        pk_next = csr[qn < qlast ? qn : qlast];  // prefetch next round
      }
      int rem = c - rb;  // wave-uniform
      int ee[32];
#pragma unroll
      for (int k = 0; k < 32; ++k) ee[k] = __builtin_amdgcn_readlane(pk, k);
      // branch-free batch of 32 independent gathers (clamped dups at tail)
      float tv[32];
#pragma unroll
      for (int k = 0; k < 32; ++k)
        tv[k] = X[(size_t)(ee[k] >> 5) * 64 + lane];
      // guarded accumulates (wave-uniform predicates)
#pragma unroll
      for (int k = 0; k < 32; ++k)
        if (k < rem && (((ee[k] >> 4) & 1) == par))
          a[(ee[k] & 15) * 64 + lane] += tv[k];
      pk = pk_next;
    }
  }
  for (int d = 0; d < 16; ++d) {
    int node = nodeBase + d;
    if (node >= n) break;
    float dn = dinv[node];
    float v = (a[d * 64 + lane] + X[(size_t)node * 64 + lane]) * dn;
    if (POOL) {
      int g = batch[node];
      atomicAdd(&gsum[(size_t)g * 64 + lane], v);
    } else {
      outv[(size_t)node * 64 + lane] = v;
    }
  }
}

// Head: per-graph wave. m = gsum/cnt; g2 = m@W2+b2; g3 = relu(g2@W3+b3);
// out = g3@W4 + b4. Node count via binary search on sorted batch.
__global__ __launch_bounds__(256) void k_head(
    const float* __restrict__ gsum, const int* __restrict__ batch,
    const float* __restrict__ W2, const float* __restrict__ b2,
    const float* __restrict__ W3, const float* __restrict__ b3,
    const float* __restrict__ W4, const float* __restrict__ b4,
    float* __restrict__ out, int ng, int n) {
  int wid = (blockIdx.x * 256 + threadIdx.x) >> 6;
  int lane = threadIdx.x & 63;
  if (wid >= ng) return;
  int lo = 0, hi = n;
  while (lo < hi) {
    int mid = (lo + hi) >> 1;
    if (batch[mid] < wid) lo = mid + 1; else hi = mid;
  }
  int lb = lo;
  hi = n;
  while (lo < hi) {
    int mid = (lo + hi) >> 1;
    if (batch[mid] <= wid) lo = mid + 1; else hi = mid;
  }
  float cden = fmaxf((float)(lo - lb), 1.0f);
  float m = gsum[(size_t)wid * 64 + lane] / cden;
  float g2 = b2[lane];
  for (int k = 0; k < 64; ++k) {
    float mk = __shfl(m, k);
    g2 += mk * W2[k * 64 + lane];
  }
  float g3 = b3[lane];
  for (int k = 0; k < 64; ++k) {
    float gk = __shfl(g2, k);
    g3 += gk * W3[k * 64 + lane];
  }
  g3 = fmaxf(g3, 0.f);
  float r = g3 * W4[lane];
  for (int off = 32; off; off >>= 1) r += __shfl_down(r, off);
  if (lane == 0) out[wid] = r + b4[0];
}

extern "C" void kernel_launch(void* const* d_in, const int* in_sizes, int n_in,
                              void* d_out, int out_size, void* d_ws, size_t ws_size,
                              hipStream_t stream) {
  const float* x = (const float*)d_in[0];
  const int* edge = (const int*)d_in[1];   // [2, E] int32
  const int* batch = (const int*)d_in[2];  // [N] int32, sorted
  const float* W1 = (const float*)d_in[3];
  const float* b1 = (const float*)d_in[4];
  const float* W2 = (const float*)d_in[5];
  const float* b2 = (const float*)d_in[6];
  const float* W3 = (const float*)d_in[7];
  const float* b3 = (const float*)d_in[8];
  const float* W4 = (const float*)d_in[9];
  const float* b4 = (const float*)d_in[10];
  float* out = (float*)d_out;

  const int n = in_sizes[0] / 64;   // 100000
  const int e = in_sizes[1] / 2;    // 1600000
  const int ng = out_size;          // 512
  const int* src = edge;
  const int* dst = edge + e;

  // Workspace layout.
  char* ws = (char*)d_ws;
  size_t off = 0;
  auto alloc = [&](size_t bytes) -> void* {
    void* p = ws + off;
    off = (off + bytes + 255) & ~(size_t)255;
    return p;
  };
  float* A = (float*)alloc((size_t)n * 64 * 4);   // P (prescaled x), then h1*dinv
  float* B = (float*)alloc((size_t)n * 64 * 4);   // agg1 out; tmp during build
  float* dinv = (float*)alloc((size_t)n * 4);
  int* blockCnt = (int*)alloc(3264 * 4);
  int* blockBase = (int*)alloc(3264 * 4);
  int* blockCursor = (int*)alloc(3264 * 4);
  int* bucketCursor = (int*)alloc(64 * 4);
  int* segLo = (int*)alloc(6400 * 4);
  int* segHi = (int*)alloc(6400 * 4);
  int* csr = (int*)alloc((size_t)e * 4);
  float* gsum = (float*)alloc((size_t)ng * 64 * 4);
  int* tmp = (int*)B;  // build-time only; B not live yet

  const int nblk = (n + 31) / 32;        // 3125 dst-blocks
  const int nbuck = (nblk + 63) / 64;    // 49 coarse buckets
  const int ntask = 2 * nblk;            // 6250 16-dst agg tasks
  const int nagg = (ntask + 1) / 2;      // agg workgroups (3125): 2 tasks/blk
  const int gsz = ng * 64;

  int zmax = gsz > nblk + 64 ? gsz : nblk + 64;
  k_init<<<(zmax + 255) / 256, 256, 0, stream>>>(gsum, blockCnt, gsz, nblk);
  k_histB<<<(e + 8191) / 8192, 256, 0, stream>>>(dst, blockCnt, e, nblk);
  k_scan<<<1, 256, 0, stream>>>(blockCnt, blockBase, blockCursor, bucketCursor,
                                nblk, nbuck);
  k_p1<<<(e + 2047) / 2048, 256, 0, stream>>>(src, dst, bucketCursor, tmp, e);
  k_p2<<<nbuck * 8, 256, 0, stream>>>(blockBase, tmp, blockCursor, csr, nblk);
  k_bsort<<<nblk, 256, 0, stream>>>(blockBase, csr, dinv, segLo, segHi, n);

  // P = x * dinv[row]   (A buffer; dead after agg1, then reused for h1*dinv)
  k_prescale<<<(n * 16 + 255) / 256, 256, 0, stream>>>(x, dinv, A, n);
  // Layer 1: B = aggS(P)
  k_agg<0><<<nagg, 128, 0, stream>>>(A, csr, segLo, segHi, dinv, batch, B,
                                     gsum, n, ntask);
  // A = relu(B@W1 + b1) * dinv[row]
  k_gemm64brs<<<(n + 63) / 64, 256, 0, stream>>>(B, W1, b1, dinv, A, n);
  // Layer 2: gsum += pooled aggS(A)
  k_agg<1><<<nagg, 128, 0, stream>>>(A, csr, segLo, segHi, dinv, batch, B,
                                     gsum, n, ntask);
  // Head: mean, @W2+b2, relu(@W3+b3), @W4+b4
  k_head<<<((size_t)ng * 64 + 255) / 256, 256, 0, stream>>>(
      gsum, batch, W2, b2, W3, b3, W4, b4, out, ng, n);
}